// Round 3
// baseline (152.196 us; speedup 1.0000x reference)
//
#include <hip/hip_runtime.h>
#include <math.h>

namespace {
constexpr int Mz = 256, Lz = 24, Sz = 22, Bz = 4;
constexpr int Wz = Mz + Lz - 1;            // 279
constexpr int ST = 23;                      // odd LDS stride -> bank spread
constexpr int TOT = Bz * Mz * Mz * Lz;      // 6291456
constexpr double SIGM_DEN = (double)Mz * (double)Wz * (double)Bz * 1e4;
}

__device__ __forceinline__ unsigned int enc_f32(float f) {
  unsigned int u = __float_as_uint(f);
  return (u & 0x80000000u) ? ~u : (u | 0x80000000u);
}
__device__ __forceinline__ float dec_f32(unsigned int e) {
  unsigned int u = (e & 0x80000000u) ? (e ^ 0x80000000u) : ~e;
  return __uint_as_float(u);
}

// Zero the reduction scalars; precompute hsum[m*256+n] = sum_s H2[m,n,s].
__global__ __launch_bounds__(256) void k_init(const float* __restrict__ H,
                                              float* __restrict__ hsum,
                                              double* __restrict__ sumsq,
                                              unsigned int* __restrict__ maxenc)
{
  int idx = blockIdx.x * 256 + threadIdx.x;
  if (idx == 0) { *sumsq = 0.0; *maxenc = 0u; }
  if (idx < Mz * Mz) {
    const float* __restrict__ hp = H + (size_t)idx * Sz;
    float a = 0.f;
    #pragma unroll
    for (int s = 0; s < Sz; ++s) a += hp[s];
    hsum[idx] = a;
  }
}

// One block per (b,m): build Y0 in LDS, accumulate sum(Y0^2), emit
// X0[n,l] = sum_s Y0[n+l,s]*H2[n,s] into d_out (used as scratch).
__global__ __launch_bounds__(256) void k_fwd(const float* __restrict__ x,
                                             const float* __restrict__ H,
                                             float* __restrict__ X0,
                                             double* __restrict__ sumsq)
{
  __shared__ float Hs[Mz * ST];   // 23552 B
  __shared__ float Ys[Wz * ST];   // 25668 B
  __shared__ float xs[Mz * Lz];   // 24576 B
  __shared__ double wred[4];

  const int b = blockIdx.x >> 8;
  const int m = blockIdx.x & 255;
  const float* __restrict__ xp = x + (size_t)(b * Mz + m) * (Mz * Lz);
  const float* __restrict__ Hp = H + (size_t)m * (Mz * Sz);

  for (int e = threadIdx.x; e < Mz * Sz; e += 256) {
    int n = e / Sz, s = e - n * Sz;
    Hs[n * ST + s] = Hp[e];                 // coalesced read, padded store
  }
  for (int e = threadIdx.x; e < Mz * Lz; e += 256) xs[e] = xp[e];
  __syncthreads();

  // ---- Y0[w,s] = sum_i Hs[w-i][s] * xs[w-i][i], thread owns one w ----
  double local = 0.0;
  for (int w = threadIdx.x; w < Wz; w += 256) {
    int i0 = w - (Mz - 1); if (i0 < 0) i0 = 0;
    int i1 = w;            if (i1 > Lz - 1) i1 = Lz - 1;
    float acc[Sz];
    #pragma unroll
    for (int s = 0; s < Sz; ++s) acc[s] = 0.f;
    for (int i = i0; i <= i1; ++i) {
      const int n = w - i;
      const float xv = xs[n * Lz + i];
      const float* __restrict__ hrow = &Hs[n * ST];
      #pragma unroll
      for (int s = 0; s < Sz; ++s) acc[s] = fmaf(hrow[s], xv, acc[s]);
    }
    float* __restrict__ yrow = &Ys[w * ST];
    #pragma unroll
    for (int s = 0; s < Sz; ++s) {
      yrow[s] = acc[s];
      local += (double)acc[s] * (double)acc[s];
    }
  }
  __syncthreads();

  // ---- block-reduce sum of squares, one atomicAdd per block ----
  for (int off = 32; off > 0; off >>= 1) local += __shfl_down(local, off, 64);
  const int lane = threadIdx.x & 63, wid = threadIdx.x >> 6;
  if (lane == 0) wred[wid] = local;
  __syncthreads();
  if (threadIdx.x == 0) atomicAdd(sumsq, wred[0] + wred[1] + wred[2] + wred[3]);

  // ---- X0[n,l] = sum_s Ys[n+l][s] * Hs[n][s] ----
  float* __restrict__ Xp = X0 + (size_t)(b * Mz + m) * (Mz * Lz);
  for (int e = threadIdx.x; e < Mz * Lz; e += 256) {
    const int n = e / Lz, l = e - n * Lz;
    const float* __restrict__ yrow = &Ys[(n + l) * ST];
    const float* __restrict__ hrow = &Hs[n * ST];
    float acc = 0.f;
    #pragma unroll
    for (int s = 0; s < Sz; ++s) acc = fmaf(yrow[s], hrow[s], acc);
    Xp[e] = acc;
  }
}

// Scan X = X0 + c*eps*hsum for the global max (X not stored; recomputed in k_final).
__global__ __launch_bounds__(256) void k_max(const float* __restrict__ X0,
                                             const float* __restrict__ eps,
                                             const float* __restrict__ hsum,
                                             const double* __restrict__ sumsq,
                                             unsigned int* __restrict__ maxenc)
{
  const float c = sqrtf((float)(*sumsq / SIGM_DEN));
  float mx = -3.4e38f;
  const int stride = gridDim.x * 256;
  for (int e = blockIdx.x * 256 + threadIdx.x; e < TOT; e += stride) {
    const int l = e % Lz;
    const int t = e / Lz;
    const int n = t & 255;
    const int bm = t >> 8;
    const int m = bm & 255;
    const float v = X0[e] + c * eps[bm * Wz + n + l] * hsum[(m << 8) + n];
    mx = fmaxf(mx, v);
  }
  for (int off = 32; off > 0; off >>= 1) mx = fmaxf(mx, __shfl_down(mx, off, 64));
  __shared__ float wred[4];
  const int lane = threadIdx.x & 63, wid = threadIdx.x >> 6;
  if (lane == 0) wred[wid] = mx;
  __syncthreads();
  if (threadIdx.x == 0) {
    float bmx = fmaxf(fmaxf(wred[0], wred[1]), fmaxf(wred[2], wred[3]));
    atomicMax(maxenc, enc_f32(bmx));
  }
}

// out = (X0 + c*eps*hsum) / max, in place over d_out.
__global__ __launch_bounds__(256) void k_final(float* __restrict__ Xio,
                                               const float* __restrict__ eps,
                                               const float* __restrict__ hsum,
                                               const double* __restrict__ sumsq,
                                               const unsigned int* __restrict__ maxenc)
{
  const float c = sqrtf((float)(*sumsq / SIGM_DEN));
  const float mx = dec_f32(*maxenc);
  const int stride = gridDim.x * 256;
  for (int e = blockIdx.x * 256 + threadIdx.x; e < TOT; e += stride) {
    const int l = e % Lz;
    const int t = e / Lz;
    const int n = t & 255;
    const int bm = t >> 8;
    const int m = bm & 255;
    const float v = Xio[e] + c * eps[bm * Wz + n + l] * hsum[(m << 8) + n];
    Xio[e] = v / mx;
  }
}

extern "C" void kernel_launch(void* const* d_in, const int* in_sizes, int n_in,
                              void* d_out, int out_size, void* d_ws, size_t ws_size,
                              hipStream_t stream) {
  const float* x   = (const float*)d_in[0];   // (4,256,256,24)
  const float* H   = (const float*)d_in[1];   // (1,256,256,1,22)
  const float* eps = (const float*)d_in[2];   // (4,256,279,1)
  float* out = (float*)d_out;                 // (4,256,256,24)

  double*       sumsq  = (double*)d_ws;
  unsigned int* maxenc = (unsigned int*)((char*)d_ws + 8);
  float*        hsum   = (float*)((char*)d_ws + 16);   // 256KB

  k_init <<<(Mz * Mz + 255) / 256, 256, 0, stream>>>(H, hsum, sumsq, maxenc);
  k_fwd  <<<Bz * Mz,              256, 0, stream>>>(x, H, out, sumsq);
  k_max  <<<1024,                 256, 0, stream>>>(out, eps, hsum, sumsq, maxenc);
  k_final<<<1024,                 256, 0, stream>>>(out, eps, hsum, sumsq, maxenc);
}